// Round 7
// baseline (552.691 us; speedup 1.0000x reference)
//
#include <hip/hip_runtime.h>
#include <hip/hip_fp16.h>
#include <math.h>

#define NN 100000
#define NE 800000
#define HH 8
#define DD 8
#define HD 64
#define CAP 32      // padded CSR row capacity; deg ~ Poisson(8), overflow negligible (validated R3-R6)

#define NBUK 200    // dst-range buckets (500 nodes each)
#define BNODES 500
#define BCAP 4400
#define P1_EPB 1024
#define P1_BLOCKS ((NE + P1_EPB - 1) / P1_EPB)   // 782
#define P2_CHUNKS 8
#define P2_CHUNK 550

#define NOCT (NN / 8)        // 12500 octets, exact
#define AGGB (NOCT / 4)      // 3125 blocks x 4 waves

// ---------------- K0: zero deg + bucket cursors + degree-hist (contiguous) ----------------

__global__ void zero_kernel(int* __restrict__ p, int n) {
    int i = blockIdx.x * 256 + threadIdx.x;
    if (i < n) p[i] = 0;
}

// ---------------- pass1: bucket edges by dst range ----------------
__global__ __launch_bounds__(256) void bucket_kernel(const int* __restrict__ src,
                                                     const int* __restrict__ dst,
                                                     int* __restrict__ cursor,
                                                     int2* __restrict__ bbuf) {
    __shared__ int hist[NBUK];
    __shared__ int base[NBUK];
    const int tid = threadIdx.x;
    for (int i = tid; i < NBUK; i += 256) hist[i] = 0;
    __syncthreads();
    const int e0 = blockIdx.x * P1_EPB;
    int myb[4], myrank[4], mysrc[4], mydst[4];
#pragma unroll
    for (int i = 0; i < 4; i++) {
        int e = e0 + tid + i * 256;
        bool v = e < NE;
        int d = v ? dst[e] : 0;
        int b = d / BNODES;
        myb[i] = b;
        mydst[i] = d;
        mysrc[i] = v ? src[e] : 0;
        myrank[i] = v ? atomicAdd(&hist[b], 1) : -1;
    }
    __syncthreads();
    for (int i = tid; i < NBUK; i += 256) {
        int c = hist[i];
        base[i] = c > 0 ? atomicAdd(&cursor[i], c) : 0;
    }
    __syncthreads();
#pragma unroll
    for (int i = 0; i < 4; i++) {
        if (myrank[i] >= 0) {
            int pos = base[myb[i]] + myrank[i];
            if (pos < BCAP) bbuf[(size_t)myb[i] * BCAP + pos] = make_int2(mysrc[i], mydst[i]);
        }
    }
}

// ---------------- pass2: per-bucket scatter into padded CSR ----------------
__global__ __launch_bounds__(256) void build_kernel(const int* __restrict__ cursor,
                                                    const int2* __restrict__ bbuf,
                                                    int* __restrict__ deg,
                                                    int* __restrict__ csr_pad) {
    const int b = blockIdx.x % NBUK;
    const int chunk = blockIdx.x / NBUK;
    const int cnt = min(cursor[b], BCAP);
    const int hi = min(chunk * P2_CHUNK + P2_CHUNK, cnt);
    const int2* bb = bbuf + (size_t)b * BCAP;
    for (int i = chunk * P2_CHUNK + threadIdx.x; i < hi; i += 256) {
        int2 p = bb[i];
        int pos = atomicAdd(&deg[p.y], 1);
        if (pos < CAP) csr_pad[(size_t)p.y * CAP + pos] = p.x;
    }
}

// ---------------- degree-sort: hist(33) -> scan -> scatter perm ----------------
// Node order within a bin is atomic-order nondeterministic, but output is
// invariant to which wave processes which node; only wave-internal cmax
// (loop trip waste) depends on it.

__global__ void dhist_kernel(const int* __restrict__ deg, int* __restrict__ hist) {
    __shared__ int h[33];
    int tid = threadIdx.x;
    if (tid < 33) h[tid] = 0;
    __syncthreads();
    int i = blockIdx.x * 256 + tid;
    if (i < NN) atomicAdd(&h[min(deg[i], CAP)], 1);
    __syncthreads();
    if (tid < 33 && h[tid] > 0) atomicAdd(&hist[tid], h[tid]);
}

__global__ void scan33_kernel(int* __restrict__ hist) {
    int lane = threadIdx.x;   // 64 threads, one wave
    int v = (lane < 33) ? hist[lane] : 0;
    int inc = v;
    for (int off = 1; off < 64; off <<= 1) {
        int t = __shfl_up(inc, off);
        if (lane >= off) inc += t;
    }
    if (lane < 33) hist[lane] = inc - v;  // exclusive base == bin cursor
}

__global__ void perm_kernel(const int* __restrict__ deg, int* __restrict__ hist,
                            int* __restrict__ perm) {
    int i = blockIdx.x * 256 + threadIdx.x;
    if (i < NN) {
        int d = min(deg[i], CAP);
        int pos = atomicAdd(&hist[d], 1);
        perm[pos] = i;
    }
}

// ---------------- lin: K-chunked LDS GEMM (unchanged from R6) ----------------
template <int K>
__global__ __launch_bounds__(256) void lin_kernel(
    const float* __restrict__ x, const float* __restrict__ W,
    const float* __restrict__ al, const float* __restrict__ ar,
    __half* __restrict__ h, float* __restrict__ el, float* __restrict__ er) {
    __shared__ float xs[64][36];
    __shared__ float ws[32][64];
    const int tid = threadIdx.x;
    const int tx = tid & 15;
    const int ty = tid >> 4;
    const int nb = blockIdx.x * 64;

    float acc[4][4];
#pragma unroll
    for (int r = 0; r < 4; r++)
#pragma unroll
        for (int c = 0; c < 4; c++) acc[r][c] = 0.f;

    for (int kc = 0; kc < K; kc += 32) {
        __syncthreads();
#pragma unroll
        for (int it = 0; it < 2; it++) {
            int idx = tid + it * 256;
            int r = idx >> 3;
            int c4 = idx & 7;
            int node = nb + r;
            if (node >= NN) node = NN - 1;
            float4 v = *(const float4*)&x[(size_t)node * K + kc + c4 * 4];
            *(float4*)&xs[r][c4 * 4] = v;
        }
#pragma unroll
        for (int it = 0; it < 2; it++) {
            int idx = tid + it * 256;
            int wr = idx >> 4;
            int wc4 = idx & 15;
            float4 v = *(const float4*)&W[(size_t)(kc + wr) * 64 + wc4 * 4];
            *(float4*)&ws[wr][wc4 * 4] = v;
        }
        __syncthreads();
#pragma unroll
        for (int kb = 0; kb < 8; kb++) {
            float4 xv[4], wv[4];
#pragma unroll
            for (int r = 0; r < 4; r++) xv[r] = *(const float4*)&xs[4 * ty + r][kb * 4];
#pragma unroll
            for (int kk = 0; kk < 4; kk++) wv[kk] = *(const float4*)&ws[kb * 4 + kk][4 * tx];
#pragma unroll
            for (int r = 0; r < 4; r++) {
#pragma unroll
                for (int kk = 0; kk < 4; kk++) {
                    float xval = ((const float*)&xv[r])[kk];
                    acc[r][0] = fmaf(xval, wv[kk].x, acc[r][0]);
                    acc[r][1] = fmaf(xval, wv[kk].y, acc[r][1]);
                    acc[r][2] = fmaf(xval, wv[kk].z, acc[r][2]);
                    acc[r][3] = fmaf(xval, wv[kk].w, acc[r][3]);
                }
            }
        }
    }

    float alv[4], arv[4];
#pragma unroll
    for (int c = 0; c < 4; c++) { alv[c] = al[4 * tx + c]; arv[c] = ar[4 * tx + c]; }
#pragma unroll
    for (int r = 0; r < 4; r++) {
        int node = nb + 4 * ty + r;
        bool ok = node < NN;
        if (ok) {
            union { __half2 h2[2]; uint2 u; } pk;
            pk.h2[0] = __floats2half2_rn(acc[r][0], acc[r][1]);
            pk.h2[1] = __floats2half2_rn(acc[r][2], acc[r][3]);
            *(uint2*)&h[(size_t)node * HD + 4 * tx] = pk.u;
        }
        float pl = 0.f, pr = 0.f;
#pragma unroll
        for (int c = 0; c < 4; c++) {
            pl = fmaf(acc[r][c], alv[c], pl);
            pr = fmaf(acc[r][c], arv[c], pr);
        }
        pl += __shfl_xor(pl, 1);
        pr += __shfl_xor(pr, 1);
        if (ok && (tx & 1) == 0) {
            int hh = tx >> 1;
            el[node * 8 + hh] = pl;
            er[node * 8 + hh] = pr;
        }
    }
}

// ---------------- fused edge softmax + aggregation: 8 nodes/wave, head/lane ----------------
// lane = (node g = lane>>3, head q = lane&7). Each lane owns head q's 8 dims:
// one uint4 (16B) hbuf load per edge, one el load + one exp per edge-head
// (zero redundancy), lane-local sum & acc -> NO cross-lane epilogue.
// CSR row staged in LDS [8][33] (padded: bank = (g+slot)%32, broadcast within
// group, conflict-free). Nodes come degree-sorted via perm -> cmax ~= cnt.
template <bool ACT>
__global__ __launch_bounds__(256) void agg_kernel(
    const __half* __restrict__ hbuf, const float* __restrict__ el,
    const float* __restrict__ er, const int* __restrict__ deg,
    const int* __restrict__ csr_pad, const int* __restrict__ perm,
    const float* __restrict__ bias, float* __restrict__ out) {
    __shared__ int rows[4][8 * 33];
    const int wave = threadIdx.x >> 6;
    const int lane = threadIdx.x & 63;
    const int oct = blockIdx.x * 4 + wave;   // 0..NOCT-1 exact (3125*4 == 12500)
    const int g = lane >> 3;
    const int q = lane & 7;
    const int node = perm[oct * 8 + g];
    const int cnt = min(deg[node], CAP);
    const float erv = er[(size_t)node * 8 + q];
    // stage this group's CSR row: 8 lanes x int4 = 128B
    int4 rv = *(const int4*)&csr_pad[(size_t)node * CAP + q * 4];
    {
        int* b = &rows[wave][g * 33 + q * 4];
        b[0] = rv.x; b[1] = rv.y; b[2] = rv.z; b[3] = rv.w;
    }
    __syncthreads();

    float4 bv0 = *(const float4*)&bias[q * 8];
    float4 bv1 = *(const float4*)&bias[q * 8 + 4];
    int cmax = cnt;
    cmax = max(cmax, __shfl_xor(cmax, 8));
    cmax = max(cmax, __shfl_xor(cmax, 16));
    cmax = max(cmax, __shfl_xor(cmax, 32));
    const int cm = max(cnt - 1, 0);
    const int* myrow = &rows[wave][g * 33];

    float4 a0 = make_float4(0.f, 0.f, 0.f, 0.f);
    float4 a1 = make_float4(0.f, 0.f, 0.f, 0.f);
    float ssum = 0.f;

    for (int jj = 0; jj < cmax; jj += 4) {
        bool v0 = jj < cnt, v1 = jj + 1 < cnt, v2 = jj + 2 < cnt, v3 = jj + 3 < cnt;
        int i0 = v0 ? jj : cm, i1 = v1 ? jj + 1 : cm;
        int i2 = v2 ? jj + 2 : cm, i3 = v3 ? jj + 3 : cm;
        int s0 = myrow[i0], s1 = myrow[i1], s2 = myrow[i2], s3 = myrow[i3];
        s0 = (unsigned)s0 < NN ? s0 : 0;
        s1 = (unsigned)s1 < NN ? s1 : 0;
        s2 = (unsigned)s2 < NN ? s2 : 0;
        s3 = (unsigned)s3 < NN ? s3 : 0;
        // issue all 8 gathers before any use
        float l0 = el[(size_t)s0 * 8 + q];
        float l1 = el[(size_t)s1 * 8 + q];
        float l2 = el[(size_t)s2 * 8 + q];
        float l3 = el[(size_t)s3 * 8 + q];
        uint4 h0 = *(const uint4*)&hbuf[(size_t)s0 * HD + q * 8];
        uint4 h1 = *(const uint4*)&hbuf[(size_t)s1 * HD + q * 8];
        uint4 h2 = *(const uint4*)&hbuf[(size_t)s2 * HD + q * 8];
        uint4 h3 = *(const uint4*)&hbuf[(size_t)s3 * HD + q * 8];

        float t0 = l0 + erv, t1 = l1 + erv, t2 = l2 + erv, t3 = l3 + erv;
        t0 = t0 > 0.f ? t0 : 0.2f * t0;
        t1 = t1 > 0.f ? t1 : 0.2f * t1;
        t2 = t2 > 0.f ? t2 : 0.2f * t2;
        t3 = t3 > 0.f ? t3 : 0.2f * t3;
        float p0 = v0 ? __expf(t0) : 0.f;
        float p1 = v1 ? __expf(t1) : 0.f;
        float p2 = v2 ? __expf(t2) : 0.f;
        float p3 = v3 ? __expf(t3) : 0.f;
        ssum += (p0 + p1) + (p2 + p3);

        {
            float2 u0 = __half22float2(*(__half2*)&h0.x), u1 = __half22float2(*(__half2*)&h0.y);
            float2 u2 = __half22float2(*(__half2*)&h0.z), u3 = __half22float2(*(__half2*)&h0.w);
            a0.x = fmaf(p0, u0.x, a0.x); a0.y = fmaf(p0, u0.y, a0.y);
            a0.z = fmaf(p0, u1.x, a0.z); a0.w = fmaf(p0, u1.y, a0.w);
            a1.x = fmaf(p0, u2.x, a1.x); a1.y = fmaf(p0, u2.y, a1.y);
            a1.z = fmaf(p0, u3.x, a1.z); a1.w = fmaf(p0, u3.y, a1.w);
        }
        {
            float2 u0 = __half22float2(*(__half2*)&h1.x), u1 = __half22float2(*(__half2*)&h1.y);
            float2 u2 = __half22float2(*(__half2*)&h1.z), u3 = __half22float2(*(__half2*)&h1.w);
            a0.x = fmaf(p1, u0.x, a0.x); a0.y = fmaf(p1, u0.y, a0.y);
            a0.z = fmaf(p1, u1.x, a0.z); a0.w = fmaf(p1, u1.y, a0.w);
            a1.x = fmaf(p1, u2.x, a1.x); a1.y = fmaf(p1, u2.y, a1.y);
            a1.z = fmaf(p1, u3.x, a1.z); a1.w = fmaf(p1, u3.y, a1.w);
        }
        {
            float2 u0 = __half22float2(*(__half2*)&h2.x), u1 = __half22float2(*(__half2*)&h2.y);
            float2 u2 = __half22float2(*(__half2*)&h2.z), u3 = __half22float2(*(__half2*)&h2.w);
            a0.x = fmaf(p2, u0.x, a0.x); a0.y = fmaf(p2, u0.y, a0.y);
            a0.z = fmaf(p2, u1.x, a0.z); a0.w = fmaf(p2, u1.y, a0.w);
            a1.x = fmaf(p2, u2.x, a1.x); a1.y = fmaf(p2, u2.y, a1.y);
            a1.z = fmaf(p2, u3.x, a1.z); a1.w = fmaf(p2, u3.y, a1.w);
        }
        {
            float2 u0 = __half22float2(*(__half2*)&h3.x), u1 = __half22float2(*(__half2*)&h3.y);
            float2 u2 = __half22float2(*(__half2*)&h3.z), u3 = __half22float2(*(__half2*)&h3.w);
            a0.x = fmaf(p3, u0.x, a0.x); a0.y = fmaf(p3, u0.y, a0.y);
            a0.z = fmaf(p3, u1.x, a0.z); a0.w = fmaf(p3, u1.y, a0.w);
            a1.x = fmaf(p3, u2.x, a1.x); a1.y = fmaf(p3, u2.y, a1.y);
            a1.z = fmaf(p3, u3.x, a1.z); a1.w = fmaf(p3, u3.y, a1.w);
        }
    }

    float inv = ssum > 0.f ? 1.f / ssum : 0.f;
    float4 o0, o1;
    o0.x = fmaf(a0.x, inv, bv0.x); o0.y = fmaf(a0.y, inv, bv0.y);
    o0.z = fmaf(a0.z, inv, bv0.z); o0.w = fmaf(a0.w, inv, bv0.w);
    o1.x = fmaf(a1.x, inv, bv1.x); o1.y = fmaf(a1.y, inv, bv1.y);
    o1.z = fmaf(a1.z, inv, bv1.z); o1.w = fmaf(a1.w, inv, bv1.w);
    if (ACT) {
        o0.x = o0.x > 0.f ? o0.x : 0.01f * o0.x;
        o0.y = o0.y > 0.f ? o0.y : 0.01f * o0.y;
        o0.z = o0.z > 0.f ? o0.z : 0.01f * o0.z;
        o0.w = o0.w > 0.f ? o0.w : 0.01f * o0.w;
        o1.x = o1.x > 0.f ? o1.x : 0.01f * o1.x;
        o1.y = o1.y > 0.f ? o1.y : 0.01f * o1.y;
        o1.z = o1.z > 0.f ? o1.z : 0.01f * o1.z;
        o1.w = o1.w > 0.f ? o1.w : 0.01f * o1.w;
    }
    *(float4*)&out[(size_t)node * HD + q * 8] = o0;
    *(float4*)&out[(size_t)node * HD + q * 8 + 4] = o1;
}

// ---------------- launch ----------------

static inline size_t al512(size_t x) { return (x + 511) & ~(size_t)511; }

extern "C" void kernel_launch(void* const* d_in, const int* in_sizes, int n_in,
                              void* d_out, int out_size, void* d_ws, size_t ws_size,
                              hipStream_t stream) {
    const float* n_feat = (const float*)d_in[0];
    const int* src = (const int*)d_in[2];
    const int* dst = (const int*)d_in[3];
    const float* W[3]  = {(const float*)d_in[4], (const float*)d_in[8],  (const float*)d_in[12]};
    const float* al[3] = {(const float*)d_in[5], (const float*)d_in[9],  (const float*)d_in[13]};
    const float* ar[3] = {(const float*)d_in[6], (const float*)d_in[10], (const float*)d_in[14]};
    const float* bs[3] = {(const float*)d_in[7], (const float*)d_in[11], (const float*)d_in[15]};
    float* outF = (float*)d_out;

    char* ws = (char*)d_ws;
    size_t off = 0;
    int* deg     = (int*)(ws + off); off += (size_t)NN * 4;      // deg+cursor+hist33 contiguous (zeroed together)
    int* cursor  = (int*)(ws + off); off += (size_t)NBUK * 4;
    int* hist33  = (int*)(ws + off); off += al512(64 * 4);
    int* csr_pad = (int*)(ws + off); off += al512((size_t)NN * CAP * 4);
    int2* bbuf   = (int2*)(ws + off); off += al512((size_t)NBUK * BCAP * 8);
    __half* hbuf = (__half*)(ws + off); off += al512((size_t)NN * HD * 2);
    float* el    = (float*)(ws + off); off += al512((size_t)NN * 8 * 4);
    float* er    = (float*)(ws + off); off += al512((size_t)NN * 8 * 4);
    int* perm    = (int*)(ws + off); off += al512((size_t)NN * 4);

    const int ZB = (NN + NBUK + 64 + 255) / 256;
    const int NB = (NN + 255) / 256;    // 391
    const int LINB = (NN + 63) / 64;    // 1563

    zero_kernel<<<ZB, 256, 0, stream>>>(deg, NN + NBUK + 64);
    bucket_kernel<<<P1_BLOCKS, 256, 0, stream>>>(src, dst, cursor, bbuf);
    build_kernel<<<NBUK * P2_CHUNKS, 256, 0, stream>>>(cursor, bbuf, deg, csr_pad);
    dhist_kernel<<<NB, 256, 0, stream>>>(deg, hist33);
    scan33_kernel<<<1, 64, 0, stream>>>(hist33);
    perm_kernel<<<NB, 256, 0, stream>>>(deg, hist33, perm);

    lin_kernel<128><<<LINB, 256, 0, stream>>>(n_feat, W[0], al[0], ar[0], hbuf, el, er);
    agg_kernel<true><<<AGGB, 256, 0, stream>>>(hbuf, el, er, deg, csr_pad, perm, bs[0], outF);
    lin_kernel<64><<<LINB, 256, 0, stream>>>(outF, W[1], al[1], ar[1], hbuf, el, er);
    agg_kernel<true><<<AGGB, 256, 0, stream>>>(hbuf, el, er, deg, csr_pad, perm, bs[1], outF);
    lin_kernel<64><<<LINB, 256, 0, stream>>>(outF, W[2], al[2], ar[2], hbuf, el, er);
    agg_kernel<false><<<AGGB, 256, 0, stream>>>(hbuf, el, er, deg, csr_pad, perm, bs[2], outF);
}

// Round 8
// 253.965 us; speedup vs baseline: 2.1762x; 2.1762x over previous
//
#include <hip/hip_runtime.h>
#include <hip/hip_fp16.h>
#include <math.h>

#define NN 100000
#define NE 800000
#define HH 8
#define DD 8
#define HD 64
#define CAP 32      // padded CSR row capacity; deg ~ Poisson(8), overflow negligible (validated R3-R7)

#define NBUK 200    // dst-range buckets (500 nodes each)
#define BNODES 500
#define BCAP 4400
#define P1_EPB 1024
#define P1_BLOCKS ((NE + P1_EPB - 1) / P1_EPB)   // 782
#define P2_CHUNKS 8
#define P2_CHUNK 550

#define NOCT (NN / 8)        // 12500 octets, exact
#define AGGB (NOCT / 4)      // 3125 blocks x 4 waves

// ---------------- K0: zero deg + bucket cursors + degree-hist (contiguous) ----------------

__global__ void zero_kernel(int* __restrict__ p, int n) {
    int i = blockIdx.x * 256 + threadIdx.x;
    if (i < n) p[i] = 0;
}

// ---------------- pass1: bucket edges by dst range ----------------
__global__ __launch_bounds__(256) void bucket_kernel(const int* __restrict__ src,
                                                     const int* __restrict__ dst,
                                                     int* __restrict__ cursor,
                                                     int2* __restrict__ bbuf) {
    __shared__ int hist[NBUK];
    __shared__ int base[NBUK];
    const int tid = threadIdx.x;
    for (int i = tid; i < NBUK; i += 256) hist[i] = 0;
    __syncthreads();
    const int e0 = blockIdx.x * P1_EPB;
    int myb[4], myrank[4], mysrc[4], mydst[4];
#pragma unroll
    for (int i = 0; i < 4; i++) {
        int e = e0 + tid + i * 256;
        bool v = e < NE;
        int d = v ? dst[e] : 0;
        int b = d / BNODES;
        myb[i] = b;
        mydst[i] = d;
        mysrc[i] = v ? src[e] : 0;
        myrank[i] = v ? atomicAdd(&hist[b], 1) : -1;
    }
    __syncthreads();
    for (int i = tid; i < NBUK; i += 256) {
        int c = hist[i];
        base[i] = c > 0 ? atomicAdd(&cursor[i], c) : 0;
    }
    __syncthreads();
#pragma unroll
    for (int i = 0; i < 4; i++) {
        if (myrank[i] >= 0) {
            int pos = base[myb[i]] + myrank[i];
            if (pos < BCAP) bbuf[(size_t)myb[i] * BCAP + pos] = make_int2(mysrc[i], mydst[i]);
        }
    }
}

// ---------------- pass2: per-bucket scatter into padded CSR ----------------
__global__ __launch_bounds__(256) void build_kernel(const int* __restrict__ cursor,
                                                    const int2* __restrict__ bbuf,
                                                    int* __restrict__ deg,
                                                    int* __restrict__ csr_pad) {
    const int b = blockIdx.x % NBUK;
    const int chunk = blockIdx.x / NBUK;
    const int cnt = min(cursor[b], BCAP);
    const int hi = min(chunk * P2_CHUNK + P2_CHUNK, cnt);
    const int2* bb = bbuf + (size_t)b * BCAP;
    for (int i = chunk * P2_CHUNK + threadIdx.x; i < hi; i += 256) {
        int2 p = bb[i];
        int pos = atomicAdd(&deg[p.y], 1);
        if (pos < CAP) csr_pad[(size_t)p.y * CAP + pos] = p.x;
    }
}

// ---------------- degree-sort: hist(33) -> scan -> hierarchical rank+scatter ----------------

__global__ void dhist_kernel(const int* __restrict__ deg, int* __restrict__ hist) {
    __shared__ int h[33];
    int tid = threadIdx.x;
    if (tid < 33) h[tid] = 0;
    __syncthreads();
    int i = blockIdx.x * 256 + tid;
    if (i < NN) atomicAdd(&h[min(deg[i], CAP)], 1);
    __syncthreads();
    if (tid < 33 && h[tid] > 0) atomicAdd(&hist[tid], h[tid]);
}

__global__ void scan33_kernel(int* __restrict__ hist) {
    int lane = threadIdx.x;   // 64 threads, one wave
    int v = (lane < 33) ? hist[lane] : 0;
    int inc = v;
    for (int off = 1; off < 64; off <<= 1) {
        int t = __shfl_up(inc, off);
        if (lane >= off) inc += t;
    }
    if (lane < 33) hist[lane] = inc - v;  // exclusive base == bin cursor
}

// R7 bug fix: per-node GLOBAL atomics on 33 bins serialized (301us).
// Hierarchical: LDS rank within block + one global atomic per (block,bin).
__global__ void perm_kernel(const int* __restrict__ deg, int* __restrict__ hist,
                            int* __restrict__ perm) {
    __shared__ int h[33];
    __shared__ int base[33];
    const int tid = threadIdx.x;
    if (tid < 33) h[tid] = 0;
    __syncthreads();
    const int i = blockIdx.x * 256 + tid;
    int d = 0, rank = -1;
    if (i < NN) {
        d = min(deg[i], CAP);
        rank = atomicAdd(&h[d], 1);
    }
    __syncthreads();
    if (tid < 33) {
        int c = h[tid];
        base[tid] = c > 0 ? atomicAdd(&hist[tid], c) : 0;
    }
    __syncthreads();
    if (rank >= 0) perm[base[d] + rank] = i;
}

// ---------------- lin: K-chunked LDS GEMM (unchanged) ----------------
template <int K>
__global__ __launch_bounds__(256) void lin_kernel(
    const float* __restrict__ x, const float* __restrict__ W,
    const float* __restrict__ al, const float* __restrict__ ar,
    __half* __restrict__ h, float* __restrict__ el, float* __restrict__ er) {
    __shared__ float xs[64][36];
    __shared__ float ws[32][64];
    const int tid = threadIdx.x;
    const int tx = tid & 15;
    const int ty = tid >> 4;
    const int nb = blockIdx.x * 64;

    float acc[4][4];
#pragma unroll
    for (int r = 0; r < 4; r++)
#pragma unroll
        for (int c = 0; c < 4; c++) acc[r][c] = 0.f;

    for (int kc = 0; kc < K; kc += 32) {
        __syncthreads();
#pragma unroll
        for (int it = 0; it < 2; it++) {
            int idx = tid + it * 256;
            int r = idx >> 3;
            int c4 = idx & 7;
            int node = nb + r;
            if (node >= NN) node = NN - 1;
            float4 v = *(const float4*)&x[(size_t)node * K + kc + c4 * 4];
            *(float4*)&xs[r][c4 * 4] = v;
        }
#pragma unroll
        for (int it = 0; it < 2; it++) {
            int idx = tid + it * 256;
            int wr = idx >> 4;
            int wc4 = idx & 15;
            float4 v = *(const float4*)&W[(size_t)(kc + wr) * 64 + wc4 * 4];
            *(float4*)&ws[wr][wc4 * 4] = v;
        }
        __syncthreads();
#pragma unroll
        for (int kb = 0; kb < 8; kb++) {
            float4 xv[4], wv[4];
#pragma unroll
            for (int r = 0; r < 4; r++) xv[r] = *(const float4*)&xs[4 * ty + r][kb * 4];
#pragma unroll
            for (int kk = 0; kk < 4; kk++) wv[kk] = *(const float4*)&ws[kb * 4 + kk][4 * tx];
#pragma unroll
            for (int r = 0; r < 4; r++) {
#pragma unroll
                for (int kk = 0; kk < 4; kk++) {
                    float xval = ((const float*)&xv[r])[kk];
                    acc[r][0] = fmaf(xval, wv[kk].x, acc[r][0]);
                    acc[r][1] = fmaf(xval, wv[kk].y, acc[r][1]);
                    acc[r][2] = fmaf(xval, wv[kk].z, acc[r][2]);
                    acc[r][3] = fmaf(xval, wv[kk].w, acc[r][3]);
                }
            }
        }
    }

    float alv[4], arv[4];
#pragma unroll
    for (int c = 0; c < 4; c++) { alv[c] = al[4 * tx + c]; arv[c] = ar[4 * tx + c]; }
#pragma unroll
    for (int r = 0; r < 4; r++) {
        int node = nb + 4 * ty + r;
        bool ok = node < NN;
        if (ok) {
            union { __half2 h2[2]; uint2 u; } pk;
            pk.h2[0] = __floats2half2_rn(acc[r][0], acc[r][1]);
            pk.h2[1] = __floats2half2_rn(acc[r][2], acc[r][3]);
            *(uint2*)&h[(size_t)node * HD + 4 * tx] = pk.u;
        }
        float pl = 0.f, pr = 0.f;
#pragma unroll
        for (int c = 0; c < 4; c++) {
            pl = fmaf(acc[r][c], alv[c], pl);
            pr = fmaf(acc[r][c], arv[c], pr);
        }
        pl += __shfl_xor(pl, 1);
        pr += __shfl_xor(pr, 1);
        if (ok && (tx & 1) == 0) {
            int hh = tx >> 1;
            el[node * 8 + hh] = pl;
            er[node * 8 + hh] = pr;
        }
    }
}

// ---------------- fused edge softmax + aggregation: 8 nodes/wave, head/lane ----------------
template <bool ACT>
__global__ __launch_bounds__(256) void agg_kernel(
    const __half* __restrict__ hbuf, const float* __restrict__ el,
    const float* __restrict__ er, const int* __restrict__ deg,
    const int* __restrict__ csr_pad, const int* __restrict__ perm,
    const float* __restrict__ bias, float* __restrict__ out) {
    __shared__ int rows[4][8 * 33];
    const int wave = threadIdx.x >> 6;
    const int lane = threadIdx.x & 63;
    const int oct = blockIdx.x * 4 + wave;   // 0..NOCT-1 exact (3125*4 == 12500)
    const int g = lane >> 3;
    const int q = lane & 7;
    const int node = perm[oct * 8 + g];
    const int cnt = min(deg[node], CAP);
    const float erv = er[(size_t)node * 8 + q];
    int4 rv = *(const int4*)&csr_pad[(size_t)node * CAP + q * 4];
    {
        int* b = &rows[wave][g * 33 + q * 4];
        b[0] = rv.x; b[1] = rv.y; b[2] = rv.z; b[3] = rv.w;
    }
    __syncthreads();

    float4 bv0 = *(const float4*)&bias[q * 8];
    float4 bv1 = *(const float4*)&bias[q * 8 + 4];
    int cmax = cnt;
    cmax = max(cmax, __shfl_xor(cmax, 8));
    cmax = max(cmax, __shfl_xor(cmax, 16));
    cmax = max(cmax, __shfl_xor(cmax, 32));
    const int cm = max(cnt - 1, 0);
    const int* myrow = &rows[wave][g * 33];

    float4 a0 = make_float4(0.f, 0.f, 0.f, 0.f);
    float4 a1 = make_float4(0.f, 0.f, 0.f, 0.f);
    float ssum = 0.f;

    for (int jj = 0; jj < cmax; jj += 4) {
        bool v0 = jj < cnt, v1 = jj + 1 < cnt, v2 = jj + 2 < cnt, v3 = jj + 3 < cnt;
        int i0 = v0 ? jj : cm, i1 = v1 ? jj + 1 : cm;
        int i2 = v2 ? jj + 2 : cm, i3 = v3 ? jj + 3 : cm;
        int s0 = myrow[i0], s1 = myrow[i1], s2 = myrow[i2], s3 = myrow[i3];
        s0 = (unsigned)s0 < NN ? s0 : 0;
        s1 = (unsigned)s1 < NN ? s1 : 0;
        s2 = (unsigned)s2 < NN ? s2 : 0;
        s3 = (unsigned)s3 < NN ? s3 : 0;
        float l0 = el[(size_t)s0 * 8 + q];
        float l1 = el[(size_t)s1 * 8 + q];
        float l2 = el[(size_t)s2 * 8 + q];
        float l3 = el[(size_t)s3 * 8 + q];
        uint4 h0 = *(const uint4*)&hbuf[(size_t)s0 * HD + q * 8];
        uint4 h1 = *(const uint4*)&hbuf[(size_t)s1 * HD + q * 8];
        uint4 h2 = *(const uint4*)&hbuf[(size_t)s2 * HD + q * 8];
        uint4 h3 = *(const uint4*)&hbuf[(size_t)s3 * HD + q * 8];

        float t0 = l0 + erv, t1 = l1 + erv, t2 = l2 + erv, t3 = l3 + erv;
        t0 = t0 > 0.f ? t0 : 0.2f * t0;
        t1 = t1 > 0.f ? t1 : 0.2f * t1;
        t2 = t2 > 0.f ? t2 : 0.2f * t2;
        t3 = t3 > 0.f ? t3 : 0.2f * t3;
        float p0 = v0 ? __expf(t0) : 0.f;
        float p1 = v1 ? __expf(t1) : 0.f;
        float p2 = v2 ? __expf(t2) : 0.f;
        float p3 = v3 ? __expf(t3) : 0.f;
        ssum += (p0 + p1) + (p2 + p3);

        {
            float2 u0 = __half22float2(*(__half2*)&h0.x), u1 = __half22float2(*(__half2*)&h0.y);
            float2 u2 = __half22float2(*(__half2*)&h0.z), u3 = __half22float2(*(__half2*)&h0.w);
            a0.x = fmaf(p0, u0.x, a0.x); a0.y = fmaf(p0, u0.y, a0.y);
            a0.z = fmaf(p0, u1.x, a0.z); a0.w = fmaf(p0, u1.y, a0.w);
            a1.x = fmaf(p0, u2.x, a1.x); a1.y = fmaf(p0, u2.y, a1.y);
            a1.z = fmaf(p0, u3.x, a1.z); a1.w = fmaf(p0, u3.y, a1.w);
        }
        {
            float2 u0 = __half22float2(*(__half2*)&h1.x), u1 = __half22float2(*(__half2*)&h1.y);
            float2 u2 = __half22float2(*(__half2*)&h1.z), u3 = __half22float2(*(__half2*)&h1.w);
            a0.x = fmaf(p1, u0.x, a0.x); a0.y = fmaf(p1, u0.y, a0.y);
            a0.z = fmaf(p1, u1.x, a0.z); a0.w = fmaf(p1, u1.y, a0.w);
            a1.x = fmaf(p1, u2.x, a1.x); a1.y = fmaf(p1, u2.y, a1.y);
            a1.z = fmaf(p1, u3.x, a1.z); a1.w = fmaf(p1, u3.y, a1.w);
        }
        {
            float2 u0 = __half22float2(*(__half2*)&h2.x), u1 = __half22float2(*(__half2*)&h2.y);
            float2 u2 = __half22float2(*(__half2*)&h2.z), u3 = __half22float2(*(__half2*)&h2.w);
            a0.x = fmaf(p2, u0.x, a0.x); a0.y = fmaf(p2, u0.y, a0.y);
            a0.z = fmaf(p2, u1.x, a0.z); a0.w = fmaf(p2, u1.y, a0.w);
            a1.x = fmaf(p2, u2.x, a1.x); a1.y = fmaf(p2, u2.y, a1.y);
            a1.z = fmaf(p2, u3.x, a1.z); a1.w = fmaf(p2, u3.y, a1.w);
        }
        {
            float2 u0 = __half22float2(*(__half2*)&h3.x), u1 = __half22float2(*(__half2*)&h3.y);
            float2 u2 = __half22float2(*(__half2*)&h3.z), u3 = __half22float2(*(__half2*)&h3.w);
            a0.x = fmaf(p3, u0.x, a0.x); a0.y = fmaf(p3, u0.y, a0.y);
            a0.z = fmaf(p3, u1.x, a0.z); a0.w = fmaf(p3, u1.y, a0.w);
            a1.x = fmaf(p3, u2.x, a1.x); a1.y = fmaf(p3, u2.y, a1.y);
            a1.z = fmaf(p3, u3.x, a1.z); a1.w = fmaf(p3, u3.y, a1.w);
        }
    }

    float inv = ssum > 0.f ? 1.f / ssum : 0.f;
    float4 o0, o1;
    o0.x = fmaf(a0.x, inv, bv0.x); o0.y = fmaf(a0.y, inv, bv0.y);
    o0.z = fmaf(a0.z, inv, bv0.z); o0.w = fmaf(a0.w, inv, bv0.w);
    o1.x = fmaf(a1.x, inv, bv1.x); o1.y = fmaf(a1.y, inv, bv1.y);
    o1.z = fmaf(a1.z, inv, bv1.z); o1.w = fmaf(a1.w, inv, bv1.w);
    if (ACT) {
        o0.x = o0.x > 0.f ? o0.x : 0.01f * o0.x;
        o0.y = o0.y > 0.f ? o0.y : 0.01f * o0.y;
        o0.z = o0.z > 0.f ? o0.z : 0.01f * o0.z;
        o0.w = o0.w > 0.f ? o0.w : 0.01f * o0.w;
        o1.x = o1.x > 0.f ? o1.x : 0.01f * o1.x;
        o1.y = o1.y > 0.f ? o1.y : 0.01f * o1.y;
        o1.z = o1.z > 0.f ? o1.z : 0.01f * o1.z;
        o1.w = o1.w > 0.f ? o1.w : 0.01f * o1.w;
    }
    *(float4*)&out[(size_t)node * HD + q * 8] = o0;
    *(float4*)&out[(size_t)node * HD + q * 8 + 4] = o1;
}

// ---------------- launch ----------------

static inline size_t al512(size_t x) { return (x + 511) & ~(size_t)511; }

extern "C" void kernel_launch(void* const* d_in, const int* in_sizes, int n_in,
                              void* d_out, int out_size, void* d_ws, size_t ws_size,
                              hipStream_t stream) {
    const float* n_feat = (const float*)d_in[0];
    const int* src = (const int*)d_in[2];
    const int* dst = (const int*)d_in[3];
    const float* W[3]  = {(const float*)d_in[4], (const float*)d_in[8],  (const float*)d_in[12]};
    const float* al[3] = {(const float*)d_in[5], (const float*)d_in[9],  (const float*)d_in[13]};
    const float* ar[3] = {(const float*)d_in[6], (const float*)d_in[10], (const float*)d_in[14]};
    const float* bs[3] = {(const float*)d_in[7], (const float*)d_in[11], (const float*)d_in[15]};
    float* outF = (float*)d_out;

    char* ws = (char*)d_ws;
    size_t off = 0;
    int* deg     = (int*)(ws + off); off += (size_t)NN * 4;      // deg+cursor+hist33 contiguous (zeroed together)
    int* cursor  = (int*)(ws + off); off += (size_t)NBUK * 4;
    int* hist33  = (int*)(ws + off); off += al512(64 * 4);
    int* csr_pad = (int*)(ws + off); off += al512((size_t)NN * CAP * 4);
    int2* bbuf   = (int2*)(ws + off); off += al512((size_t)NBUK * BCAP * 8);
    __half* hbuf = (__half*)(ws + off); off += al512((size_t)NN * HD * 2);
    float* el    = (float*)(ws + off); off += al512((size_t)NN * 8 * 4);
    float* er    = (float*)(ws + off); off += al512((size_t)NN * 8 * 4);
    int* perm    = (int*)(ws + off); off += al512((size_t)NN * 4);

    const int ZB = (NN + NBUK + 64 + 255) / 256;
    const int NB = (NN + 255) / 256;    // 391
    const int LINB = (NN + 63) / 64;    // 1563

    zero_kernel<<<ZB, 256, 0, stream>>>(deg, NN + NBUK + 64);
    bucket_kernel<<<P1_BLOCKS, 256, 0, stream>>>(src, dst, cursor, bbuf);
    build_kernel<<<NBUK * P2_CHUNKS, 256, 0, stream>>>(cursor, bbuf, deg, csr_pad);
    dhist_kernel<<<NB, 256, 0, stream>>>(deg, hist33);
    scan33_kernel<<<1, 64, 0, stream>>>(hist33);
    perm_kernel<<<NB, 256, 0, stream>>>(deg, hist33, perm);

    lin_kernel<128><<<LINB, 256, 0, stream>>>(n_feat, W[0], al[0], ar[0], hbuf, el, er);
    agg_kernel<true><<<AGGB, 256, 0, stream>>>(hbuf, el, er, deg, csr_pad, perm, bs[0], outF);
    lin_kernel<64><<<LINB, 256, 0, stream>>>(outF, W[1], al[1], ar[1], hbuf, el, er);
    agg_kernel<true><<<AGGB, 256, 0, stream>>>(hbuf, el, er, deg, csr_pad, perm, bs[1], outF);
    lin_kernel<64><<<LINB, 256, 0, stream>>>(outF, W[2], al[2], ar[2], hbuf, el, er);
    agg_kernel<false><<<AGGB, 256, 0, stream>>>(hbuf, el, er, deg, csr_pad, perm, bs[2], outF);
}

// Round 9
// 197.864 us; speedup vs baseline: 2.7933x; 1.2835x over previous
//
#include <hip/hip_runtime.h>
#include <hip/hip_fp16.h>
#include <math.h>

#define NN 100000
#define NE 800000
#define HH 8
#define DD 8
#define HD 64
#define CAP 32      // padded CSR row capacity; deg ~ Poisson(8), overflow negligible (validated R3-R8)

#define NBUK 200    // dst-range buckets (500 nodes each)
#define BNODES 500
#define BCAP 4400
#define P1_EPB 1024
#define P1_BLOCKS ((NE + P1_EPB - 1) / P1_EPB)   // 782
#define P2_CHUNKS 8
#define P2_CHUNK 550

#define NOCT (NN / 8)        // 12500 octets, exact
#define AGGB (NOCT / 4)      // 3125 blocks x 4 waves

// ---------------- K0: zero deg + bucket cursors (contiguous) ----------------

__global__ void zero_kernel(int* __restrict__ p, int n) {
    int i = blockIdx.x * 256 + threadIdx.x;
    if (i < n) p[i] = 0;
}

// ---------------- pass1: bucket edges by dst range ----------------
__global__ __launch_bounds__(256) void bucket_kernel(const int* __restrict__ src,
                                                     const int* __restrict__ dst,
                                                     int* __restrict__ cursor,
                                                     int2* __restrict__ bbuf) {
    __shared__ int hist[NBUK];
    __shared__ int base[NBUK];
    const int tid = threadIdx.x;
    for (int i = tid; i < NBUK; i += 256) hist[i] = 0;
    __syncthreads();
    const int e0 = blockIdx.x * P1_EPB;
    int myb[4], myrank[4], mysrc[4], mydst[4];
#pragma unroll
    for (int i = 0; i < 4; i++) {
        int e = e0 + tid + i * 256;
        bool v = e < NE;
        int d = v ? dst[e] : 0;
        int b = d / BNODES;
        myb[i] = b;
        mydst[i] = d;
        mysrc[i] = v ? src[e] : 0;
        myrank[i] = v ? atomicAdd(&hist[b], 1) : -1;
    }
    __syncthreads();
    for (int i = tid; i < NBUK; i += 256) {
        int c = hist[i];
        base[i] = c > 0 ? atomicAdd(&cursor[i], c) : 0;
    }
    __syncthreads();
#pragma unroll
    for (int i = 0; i < 4; i++) {
        if (myrank[i] >= 0) {
            int pos = base[myb[i]] + myrank[i];
            if (pos < BCAP) bbuf[(size_t)myb[i] * BCAP + pos] = make_int2(mysrc[i], mydst[i]);
        }
    }
}

// ---------------- pass2: per-bucket scatter into padded CSR ----------------
__global__ __launch_bounds__(256) void build_kernel(const int* __restrict__ cursor,
                                                    const int2* __restrict__ bbuf,
                                                    int* __restrict__ deg,
                                                    int* __restrict__ csr_pad) {
    const int b = blockIdx.x % NBUK;
    const int chunk = blockIdx.x / NBUK;
    const int cnt = min(cursor[b], BCAP);
    const int hi = min(chunk * P2_CHUNK + P2_CHUNK, cnt);
    const int2* bb = bbuf + (size_t)b * BCAP;
    for (int i = chunk * P2_CHUNK + threadIdx.x; i < hi; i += 256) {
        int2 p = bb[i];
        int pos = atomicAdd(&deg[p.y], 1);
        if (pos < CAP) csr_pad[(size_t)p.y * CAP + pos] = p.x;
    }
}

// ---------------- lin: K-chunked LDS GEMM (unchanged) ----------------
template <int K>
__global__ __launch_bounds__(256) void lin_kernel(
    const float* __restrict__ x, const float* __restrict__ W,
    const float* __restrict__ al, const float* __restrict__ ar,
    __half* __restrict__ h, float* __restrict__ el, float* __restrict__ er) {
    __shared__ float xs[64][36];
    __shared__ float ws[32][64];
    const int tid = threadIdx.x;
    const int tx = tid & 15;
    const int ty = tid >> 4;
    const int nb = blockIdx.x * 64;

    float acc[4][4];
#pragma unroll
    for (int r = 0; r < 4; r++)
#pragma unroll
        for (int c = 0; c < 4; c++) acc[r][c] = 0.f;

    for (int kc = 0; kc < K; kc += 32) {
        __syncthreads();
#pragma unroll
        for (int it = 0; it < 2; it++) {
            int idx = tid + it * 256;
            int r = idx >> 3;
            int c4 = idx & 7;
            int node = nb + r;
            if (node >= NN) node = NN - 1;
            float4 v = *(const float4*)&x[(size_t)node * K + kc + c4 * 4];
            *(float4*)&xs[r][c4 * 4] = v;
        }
#pragma unroll
        for (int it = 0; it < 2; it++) {
            int idx = tid + it * 256;
            int wr = idx >> 4;
            int wc4 = idx & 15;
            float4 v = *(const float4*)&W[(size_t)(kc + wr) * 64 + wc4 * 4];
            *(float4*)&ws[wr][wc4 * 4] = v;
        }
        __syncthreads();
#pragma unroll
        for (int kb = 0; kb < 8; kb++) {
            float4 xv[4], wv[4];
#pragma unroll
            for (int r = 0; r < 4; r++) xv[r] = *(const float4*)&xs[4 * ty + r][kb * 4];
#pragma unroll
            for (int kk = 0; kk < 4; kk++) wv[kk] = *(const float4*)&ws[kb * 4 + kk][4 * tx];
#pragma unroll
            for (int r = 0; r < 4; r++) {
#pragma unroll
                for (int kk = 0; kk < 4; kk++) {
                    float xval = ((const float*)&xv[r])[kk];
                    acc[r][0] = fmaf(xval, wv[kk].x, acc[r][0]);
                    acc[r][1] = fmaf(xval, wv[kk].y, acc[r][1]);
                    acc[r][2] = fmaf(xval, wv[kk].z, acc[r][2]);
                    acc[r][3] = fmaf(xval, wv[kk].w, acc[r][3]);
                }
            }
        }
    }

    float alv[4], arv[4];
#pragma unroll
    for (int c = 0; c < 4; c++) { alv[c] = al[4 * tx + c]; arv[c] = ar[4 * tx + c]; }
#pragma unroll
    for (int r = 0; r < 4; r++) {
        int node = nb + 4 * ty + r;
        bool ok = node < NN;
        if (ok) {
            union { __half2 h2[2]; uint2 u; } pk;
            pk.h2[0] = __floats2half2_rn(acc[r][0], acc[r][1]);
            pk.h2[1] = __floats2half2_rn(acc[r][2], acc[r][3]);
            *(uint2*)&h[(size_t)node * HD + 4 * tx] = pk.u;
        }
        float pl = 0.f, pr = 0.f;
#pragma unroll
        for (int c = 0; c < 4; c++) {
            pl = fmaf(acc[r][c], alv[c], pl);
            pr = fmaf(acc[r][c], arv[c], pr);
        }
        pl += __shfl_xor(pl, 1);
        pr += __shfl_xor(pr, 1);
        if (ok && (tx & 1) == 0) {
            int hh = tx >> 1;
            el[node * 8 + hh] = pl;
            er[node * 8 + hh] = pr;
        }
    }
}

// ---------------- fused edge softmax + aggregation: 8 nodes/wave, head/lane ----------------
// R9: NATURAL node order (node = oct*8+g) -- degree-sort perm removed (R8
// ablation: it scattered dst-side lines and cost +54MB FETCH). dst-side
// accesses are contiguous per wave: deg 32B, er 256B, csr 1KB, out 2KB.
// Unequal degrees in an octet waste clamped slots (dup lines -> L2 hits,
// no extra FETCH; VALU was only 16% busy).
template <bool ACT>
__global__ __launch_bounds__(256) void agg_kernel(
    const __half* __restrict__ hbuf, const float* __restrict__ el,
    const float* __restrict__ er, const int* __restrict__ deg,
    const int* __restrict__ csr_pad, const float* __restrict__ bias,
    float* __restrict__ out) {
    __shared__ int rows[4][8 * 33];
    const int wave = threadIdx.x >> 6;
    const int lane = threadIdx.x & 63;
    const int oct = blockIdx.x * 4 + wave;   // 0..NOCT-1 exact (3125*4 == 12500)
    const int g = lane >> 3;
    const int q = lane & 7;
    const int node = oct * 8 + g;
    const int cnt = min(deg[node], CAP);
    const float erv = er[(size_t)node * 8 + q];
    int4 rv = *(const int4*)&csr_pad[(size_t)node * CAP + q * 4];
    {
        int* b = &rows[wave][g * 33 + q * 4];
        b[0] = rv.x; b[1] = rv.y; b[2] = rv.z; b[3] = rv.w;
    }
    __syncthreads();

    float4 bv0 = *(const float4*)&bias[q * 8];
    float4 bv1 = *(const float4*)&bias[q * 8 + 4];
    int cmax = cnt;
    cmax = max(cmax, __shfl_xor(cmax, 8));
    cmax = max(cmax, __shfl_xor(cmax, 16));
    cmax = max(cmax, __shfl_xor(cmax, 32));
    const int cm = max(cnt - 1, 0);
    const int* myrow = &rows[wave][g * 33];

    float4 a0 = make_float4(0.f, 0.f, 0.f, 0.f);
    float4 a1 = make_float4(0.f, 0.f, 0.f, 0.f);
    float ssum = 0.f;

    for (int jj = 0; jj < cmax; jj += 4) {
        bool v0 = jj < cnt, v1 = jj + 1 < cnt, v2 = jj + 2 < cnt, v3 = jj + 3 < cnt;
        int i0 = v0 ? jj : cm, i1 = v1 ? jj + 1 : cm;
        int i2 = v2 ? jj + 2 : cm, i3 = v3 ? jj + 3 : cm;
        int s0 = myrow[i0], s1 = myrow[i1], s2 = myrow[i2], s3 = myrow[i3];
        s0 = (unsigned)s0 < NN ? s0 : 0;
        s1 = (unsigned)s1 < NN ? s1 : 0;
        s2 = (unsigned)s2 < NN ? s2 : 0;
        s3 = (unsigned)s3 < NN ? s3 : 0;
        float l0 = el[(size_t)s0 * 8 + q];
        float l1 = el[(size_t)s1 * 8 + q];
        float l2 = el[(size_t)s2 * 8 + q];
        float l3 = el[(size_t)s3 * 8 + q];
        uint4 h0 = *(const uint4*)&hbuf[(size_t)s0 * HD + q * 8];
        uint4 h1 = *(const uint4*)&hbuf[(size_t)s1 * HD + q * 8];
        uint4 h2 = *(const uint4*)&hbuf[(size_t)s2 * HD + q * 8];
        uint4 h3 = *(const uint4*)&hbuf[(size_t)s3 * HD + q * 8];

        float t0 = l0 + erv, t1 = l1 + erv, t2 = l2 + erv, t3 = l3 + erv;
        t0 = t0 > 0.f ? t0 : 0.2f * t0;
        t1 = t1 > 0.f ? t1 : 0.2f * t1;
        t2 = t2 > 0.f ? t2 : 0.2f * t2;
        t3 = t3 > 0.f ? t3 : 0.2f * t3;
        float p0 = v0 ? __expf(t0) : 0.f;
        float p1 = v1 ? __expf(t1) : 0.f;
        float p2 = v2 ? __expf(t2) : 0.f;
        float p3 = v3 ? __expf(t3) : 0.f;
        ssum += (p0 + p1) + (p2 + p3);

        {
            float2 u0 = __half22float2(*(__half2*)&h0.x), u1 = __half22float2(*(__half2*)&h0.y);
            float2 u2 = __half22float2(*(__half2*)&h0.z), u3 = __half22float2(*(__half2*)&h0.w);
            a0.x = fmaf(p0, u0.x, a0.x); a0.y = fmaf(p0, u0.y, a0.y);
            a0.z = fmaf(p0, u1.x, a0.z); a0.w = fmaf(p0, u1.y, a0.w);
            a1.x = fmaf(p0, u2.x, a1.x); a1.y = fmaf(p0, u2.y, a1.y);
            a1.z = fmaf(p0, u3.x, a1.z); a1.w = fmaf(p0, u3.y, a1.w);
        }
        {
            float2 u0 = __half22float2(*(__half2*)&h1.x), u1 = __half22float2(*(__half2*)&h1.y);
            float2 u2 = __half22float2(*(__half2*)&h1.z), u3 = __half22float2(*(__half2*)&h1.w);
            a0.x = fmaf(p1, u0.x, a0.x); a0.y = fmaf(p1, u0.y, a0.y);
            a0.z = fmaf(p1, u1.x, a0.z); a0.w = fmaf(p1, u1.y, a0.w);
            a1.x = fmaf(p1, u2.x, a1.x); a1.y = fmaf(p1, u2.y, a1.y);
            a1.z = fmaf(p1, u3.x, a1.z); a1.w = fmaf(p1, u3.y, a1.w);
        }
        {
            float2 u0 = __half22float2(*(__half2*)&h2.x), u1 = __half22float2(*(__half2*)&h2.y);
            float2 u2 = __half22float2(*(__half2*)&h2.z), u3 = __half22float2(*(__half2*)&h2.w);
            a0.x = fmaf(p2, u0.x, a0.x); a0.y = fmaf(p2, u0.y, a0.y);
            a0.z = fmaf(p2, u1.x, a0.z); a0.w = fmaf(p2, u1.y, a0.w);
            a1.x = fmaf(p2, u2.x, a1.x); a1.y = fmaf(p2, u2.y, a1.y);
            a1.z = fmaf(p2, u3.x, a1.z); a1.w = fmaf(p2, u3.y, a1.w);
        }
        {
            float2 u0 = __half22float2(*(__half2*)&h3.x), u1 = __half22float2(*(__half2*)&h3.y);
            float2 u2 = __half22float2(*(__half2*)&h3.z), u3 = __half22float2(*(__half2*)&h3.w);
            a0.x = fmaf(p3, u0.x, a0.x); a0.y = fmaf(p3, u0.y, a0.y);
            a0.z = fmaf(p3, u1.x, a0.z); a0.w = fmaf(p3, u1.y, a0.w);
            a1.x = fmaf(p3, u2.x, a1.x); a1.y = fmaf(p3, u2.y, a1.y);
            a1.z = fmaf(p3, u3.x, a1.z); a1.w = fmaf(p3, u3.y, a1.w);
        }
    }

    float inv = ssum > 0.f ? 1.f / ssum : 0.f;
    float4 o0, o1;
    o0.x = fmaf(a0.x, inv, bv0.x); o0.y = fmaf(a0.y, inv, bv0.y);
    o0.z = fmaf(a0.z, inv, bv0.z); o0.w = fmaf(a0.w, inv, bv0.w);
    o1.x = fmaf(a1.x, inv, bv1.x); o1.y = fmaf(a1.y, inv, bv1.y);
    o1.z = fmaf(a1.z, inv, bv1.z); o1.w = fmaf(a1.w, inv, bv1.w);
    if (ACT) {
        o0.x = o0.x > 0.f ? o0.x : 0.01f * o0.x;
        o0.y = o0.y > 0.f ? o0.y : 0.01f * o0.y;
        o0.z = o0.z > 0.f ? o0.z : 0.01f * o0.z;
        o0.w = o0.w > 0.f ? o0.w : 0.01f * o0.w;
        o1.x = o1.x > 0.f ? o1.x : 0.01f * o1.x;
        o1.y = o1.y > 0.f ? o1.y : 0.01f * o1.y;
        o1.z = o1.z > 0.f ? o1.z : 0.01f * o1.z;
        o1.w = o1.w > 0.f ? o1.w : 0.01f * o1.w;
    }
    *(float4*)&out[(size_t)node * HD + q * 8] = o0;
    *(float4*)&out[(size_t)node * HD + q * 8 + 4] = o1;
}

// ---------------- launch ----------------

static inline size_t al512(size_t x) { return (x + 511) & ~(size_t)511; }

extern "C" void kernel_launch(void* const* d_in, const int* in_sizes, int n_in,
                              void* d_out, int out_size, void* d_ws, size_t ws_size,
                              hipStream_t stream) {
    const float* n_feat = (const float*)d_in[0];
    const int* src = (const int*)d_in[2];
    const int* dst = (const int*)d_in[3];
    const float* W[3]  = {(const float*)d_in[4], (const float*)d_in[8],  (const float*)d_in[12]};
    const float* al[3] = {(const float*)d_in[5], (const float*)d_in[9],  (const float*)d_in[13]};
    const float* ar[3] = {(const float*)d_in[6], (const float*)d_in[10], (const float*)d_in[14]};
    const float* bs[3] = {(const float*)d_in[7], (const float*)d_in[11], (const float*)d_in[15]};
    float* outF = (float*)d_out;

    char* ws = (char*)d_ws;
    size_t off = 0;
    int* deg     = (int*)(ws + off); off += (size_t)NN * 4;      // deg+cursor contiguous (zeroed together)
    int* cursor  = (int*)(ws + off); off += al512((size_t)NBUK * 4);
    int* csr_pad = (int*)(ws + off); off += al512((size_t)NN * CAP * 4);
    int2* bbuf   = (int2*)(ws + off); off += al512((size_t)NBUK * BCAP * 8);
    __half* hbuf = (__half*)(ws + off); off += al512((size_t)NN * HD * 2);
    float* el    = (float*)(ws + off); off += al512((size_t)NN * 8 * 4);
    float* er    = (float*)(ws + off); off += al512((size_t)NN * 8 * 4);

    const int ZB = (NN + NBUK + 255) / 256;
    const int LINB = (NN + 63) / 64;    // 1563

    zero_kernel<<<ZB, 256, 0, stream>>>(deg, NN + NBUK);
    bucket_kernel<<<P1_BLOCKS, 256, 0, stream>>>(src, dst, cursor, bbuf);
    build_kernel<<<NBUK * P2_CHUNKS, 256, 0, stream>>>(cursor, bbuf, deg, csr_pad);

    lin_kernel<128><<<LINB, 256, 0, stream>>>(n_feat, W[0], al[0], ar[0], hbuf, el, er);
    agg_kernel<true><<<AGGB, 256, 0, stream>>>(hbuf, el, er, deg, csr_pad, bs[0], outF);
    lin_kernel<64><<<LINB, 256, 0, stream>>>(outF, W[1], al[1], ar[1], hbuf, el, er);
    agg_kernel<true><<<AGGB, 256, 0, stream>>>(hbuf, el, er, deg, csr_pad, bs[1], outF);
    lin_kernel<64><<<LINB, 256, 0, stream>>>(outF, W[2], al[2], ar[2], hbuf, el, er);
    agg_kernel<false><<<AGGB, 256, 0, stream>>>(hbuf, el, er, deg, csr_pad, bs[2], outF);
}